// Round 1
// baseline (878.479 us; speedup 1.0000x reference)
//
#include <hip/hip_runtime.h>
#include <hip/hip_bf16.h>
#include <stdint.h>

// Problem constants (B=32, T=128, F=1024, CONV=2048, SHORT=2048, RATE=4)
// out[b, r, f] layout: 4096 rows/batch, 1024 floats/row = 256 float4/row.
//   r in [0,2016)    <- memory[b, r+32]
//   r in [2016,2048) <- conv output (GEMM blocks)
//   r in [2048,3968) <- memory[b, r+128]
//   r in [3968,4096) <- inputs[b, r-3968]
// Conv as GEMM: C[M=1024][N=1024] = A[M][K=4096] @ W[K][N], A row m=b*32+to is
// the contiguous fp32 block memory[b, 2048+4*to .. +4, :]; W = conv_w flat.

#define AS1 __attribute__((address_space(1)))
#define AS3 __attribute__((address_space(3)))

typedef __attribute__((ext_vector_type(8))) short bf16x8;
typedef __attribute__((ext_vector_type(4))) float f32x4;

__device__ __forceinline__ unsigned short f2bf(float x) {
  union { float f; unsigned u; } v; v.f = x;
  unsigned u = v.u;
  unsigned r = (u + 0x7fffu + ((u >> 16) & 1u)) >> 16;  // RNE
  return (unsigned short)r;
}

__device__ __forceinline__ void lds_load16(const void* g, void* l) {
  __builtin_amdgcn_global_load_lds((AS1 void*)(g), (AS3 void*)(l), 16, 0, 0);
}

// ---- prep: blocks [0,4096) cast A rows to bf16; [4096,8192) transpose W to bf16 Wt[N][K]
__global__ __launch_bounds__(256) void prep_kernel(const float* __restrict__ mem,
                                                   const float* __restrict__ W,
                                                   unsigned short* __restrict__ A16,
                                                   unsigned short* __restrict__ Wt16) {
  __shared__ float tl[32][33];
  if (blockIdx.x < 4096) {
    // A16 flat per batch == memory[b, 2048:2176, :] flat (131072 floats), cast to bf16
    int idx = blockIdx.x * 256 + threadIdx.x;      // [0, 1048576) float4 chunks
    int b = idx >> 15;                             // 32768 float4 per batch
    int rem = idx & 32767;
    float4 v = reinterpret_cast<const float4*>(mem)[(size_t)(b * 4096 + 2048) * 256 + rem];
    ushort4 o;
    o.x = f2bf(v.x); o.y = f2bf(v.y); o.z = f2bf(v.z); o.w = f2bf(v.w);
    reinterpret_cast<ushort4*>(A16)[(size_t)b * 32768 + rem] = o;
  } else {
    // Wt[n][k] = W[k][n], 32x32 LDS tiles, coalesced both sides
    int tid = blockIdx.x - 4096;                   // 128 k-tiles x 32 n-tiles
    int tile_n = tid >> 7;
    int tile_k = tid & 127;
    int tx = threadIdx.x & 31, ty = threadIdx.x >> 5;
    int k0 = tile_k * 32, n0 = tile_n * 32;
#pragma unroll
    for (int i = 0; i < 4; ++i)
      tl[ty + i * 8][tx] = W[(size_t)(k0 + ty + i * 8) * 1024 + n0 + tx];
    __syncthreads();
#pragma unroll
    for (int i = 0; i < 4; ++i) {
      int nr = ty + i * 8;
      Wt16[(size_t)(n0 + nr) * 4096 + k0 + tx] = f2bf(tl[tx][nr]);
    }
  }
}

// ---- fused: blocks [0,64) = GEMM 128x128 tiles; blocks [64,8256) = float4 copy
__global__ __launch_bounds__(256) void fused_kernel(
    const float* __restrict__ mem, const float* __restrict__ inp,
    const float* __restrict__ bias,
    const unsigned short* __restrict__ A16, const unsigned short* __restrict__ Wt16,
    float* __restrict__ out) {
  if (blockIdx.x < 64) {
    __shared__ unsigned short Als[128 * 32];
    __shared__ unsigned short Bls[128 * 32];
    const int t = threadIdx.x;
    const int m0 = (int)(blockIdx.x & 7) * 128;
    const int n0 = (int)(blockIdx.x >> 3) * 128;
    const int w = t >> 6, lane = t & 63;
    const int wm = w & 1, wn = w >> 1;           // 2x2 waves, each 64x64
    const int lrow = lane & 15, lq = lane >> 4;
    f32x4 acc[4][4] = {};

    // staging: 512 chunks of 16B per matrix per K-iter; thread t handles chunks t, 256+t
    const int c0 = t, c1 = 256 + t;
    const unsigned short* gA0 = A16 + (size_t)(m0 + (c0 >> 2)) * 4096 + (c0 & 3) * 8;
    const unsigned short* gA1 = A16 + (size_t)(m0 + (c1 >> 2)) * 4096 + (c1 & 3) * 8;
    const unsigned short* gB0 = Wt16 + (size_t)(n0 + (c0 >> 2)) * 4096 + (c0 & 3) * 8;
    const unsigned short* gB1 = Wt16 + (size_t)(n0 + (c1 >> 2)) * 4096 + (c1 & 3) * 8;
    unsigned short* lA0 = &Als[c0 * 8];
    unsigned short* lA1 = &Als[c1 * 8];
    unsigned short* lB0 = &Bls[c0 * 8];
    unsigned short* lB1 = &Bls[c1 * 8];

    for (int kk = 0; kk < 128; ++kk) {
      const int ko = kk * 32;
      lds_load16(gA0 + ko, lA0);
      lds_load16(gA1 + ko, lA1);
      lds_load16(gB0 + ko, lB0);
      lds_load16(gB1 + ko, lB1);
      __syncthreads();
      bf16x8 af[4], bfr[4];
#pragma unroll
      for (int mi = 0; mi < 4; ++mi)
        af[mi] = *reinterpret_cast<const bf16x8*>(&Als[(wm * 64 + mi * 16 + lrow) * 32 + lq * 8]);
#pragma unroll
      for (int ni = 0; ni < 4; ++ni)
        bfr[ni] = *reinterpret_cast<const bf16x8*>(&Bls[(wn * 64 + ni * 16 + lrow) * 32 + lq * 8]);
#pragma unroll
      for (int mi = 0; mi < 4; ++mi)
#pragma unroll
        for (int ni = 0; ni < 4; ++ni)
          acc[mi][ni] = __builtin_amdgcn_mfma_f32_16x16x32_bf16(af[mi], bfr[ni], acc[mi][ni], 0, 0, 0);
      __syncthreads();
    }

    // epilogue: C/D layout col=lane&15, row=lq*4+reg
#pragma unroll
    for (int ni = 0; ni < 4; ++ni) {
      const int gn = n0 + wn * 64 + ni * 16 + lrow;
      const float bv = bias[gn];
#pragma unroll
      for (int mi = 0; mi < 4; ++mi) {
        f32x4 a = acc[mi][ni];
#pragma unroll
        for (int r2 = 0; r2 < 4; ++r2) {
          const int gm = m0 + wm * 64 + mi * 16 + lq * 4 + r2;
          const int bb = gm >> 5, to = gm & 31;
          out[((size_t)(bb * 4096 + 2016 + to)) * 1024 + gn] = a[r2] + bv;
        }
      }
    }
  } else {
    const int t = ((int)blockIdx.x - 64) * 256 + threadIdx.x;  // [0, 2097152)
    const float4* mem4 = reinterpret_cast<const float4*>(mem);
    const float4* in4 = reinterpret_cast<const float4*>(inp);
    float4* out4 = reinterpret_cast<float4*>(out);
#pragma unroll
    for (int i = 0; i < 16; ++i) {
      int idx = i * 2097152 + t;        // [0, 2^25) output float4 index
      int b = idx >> 20;
      int r = (idx >> 8) & 4095;
      int c = idx & 255;
      size_t obase = (size_t)b << 20;
      float4 v;
      if (r < 2016)       v = mem4[obase + ((size_t)(r + 32) << 8) + c];
      else if (r >= 3968) v = in4[((size_t)(b << 7) + (r - 3968)) * 256 + c];
      else if (r >= 2048) v = mem4[obase + ((size_t)(r + 128) << 8) + c];
      else continue;                    // conv rows: written by GEMM blocks
      out4[idx] = v;
    }
  }
}

extern "C" void kernel_launch(void* const* d_in, const int* in_sizes, int n_in,
                              void* d_out, int out_size, void* d_ws, size_t ws_size,
                              hipStream_t stream) {
  (void)in_sizes; (void)n_in; (void)out_size; (void)ws_size;
  const float* inputs = (const float*)d_in[0];
  const float* memory = (const float*)d_in[1];
  const float* conv_w = (const float*)d_in[2];
  const float* conv_b = (const float*)d_in[3];
  unsigned short* A16 = (unsigned short*)d_ws;                    // 1024x4096 bf16 = 8 MB
  unsigned short* Wt16 = A16 + (size_t)1024 * 4096;               // 1024x4096 bf16 = 8 MB

  prep_kernel<<<8192, 256, 0, stream>>>(memory, conv_w, A16, Wt16);
  fused_kernel<<<64 + 8192, 256, 0, stream>>>(memory, inputs, conv_b, A16, Wt16, (float*)d_out);
}